// Round 2
// baseline (691.387 us; speedup 1.0000x reference)
//
#include <hip/hip_runtime.h>
#include <hip/hip_bf16.h>

// ---------------- problem constants ----------------
constexpr int Bc  = 4;
constexpr int Sc  = 1024;
constexpr int Hc  = 1536;
constexpr int NHc = 24;
constexpr int P2c = 512;            // 2*ATT_SPAN
constexpr int MX  = Bc * Sc;        // 4096 rows of X
constexpr int MA  = MX + P2c;       // 4608 rows of [X ; rel_emb]
constexpr int N3  = 3 * Hc;         // 4608 output cols (q|k|v)
constexpr float INV_SCALE = 0.07216878364870323f;  // 1/sqrt(64*3)

using f32x4  = __attribute__((ext_vector_type(4))) float;
using bf16x8 = __attribute__((ext_vector_type(8))) short;
using i32x4  = __attribute__((ext_vector_type(4))) int;
using u16x8  = __attribute__((ext_vector_type(8))) unsigned short;
using u16x4  = __attribute__((ext_vector_type(4))) unsigned short;
typedef unsigned short u16;

#define DEV __device__ __forceinline__

DEV float bf2f(u16 u) { return __uint_as_float(((unsigned)u) << 16); }
DEV u16   f2bf(float f) { return __builtin_bit_cast(unsigned short, __float2bfloat16(f)); }

#if defined(__has_builtin)
#if __has_builtin(__builtin_amdgcn_global_load_lds)
#define HAVE_GLL 1
#endif
#endif
#ifndef HAVE_GLL
#define HAVE_GLL 0
#endif

// Stage 32 rows x 64 bf16 cols of a row-major (stride ldk) global tile into LDS.
DEV void stage32(u16* lds, const u16* g, int ldk, int lane) {
#pragma unroll
  for (int c = 0; c < 4; ++c) {
    const int row   = c * 8 + (lane >> 3);
    const int gslot = (lane & 7) ^ (row & 7);          // pre-swizzled source (rule 21)
    const u16* gp = g + (size_t)row * ldk + gslot * 8;
#if HAVE_GLL
    __builtin_amdgcn_global_load_lds(
        (const __attribute__((address_space(1))) void*)gp,
        (__attribute__((address_space(3))) void*)(lds + c * 8 * 64),
        16, 0, 0);
#else
    i32x4 v = *(const i32x4*)gp;
    *(i32x4*)(lds + row * 64 + (lane & 7) * 8) = v;
#endif
  }
}

DEV bf16x8 ldsFrag(const u16* base, int row, int kh, int lhi) {
  const int idx = row * 64 + ((kh * 32 + lhi * 8) ^ ((row & 7) * 8));
  return *(const bf16x8*)(base + idx);
}

// ---------------- GEMM: C[M,N] = A[M,K=1536] @ Bt[N,K]^T  (+ epilogue) ----------------
template <int MODE>
__global__ __launch_bounds__(256) void gemm128(
    const u16* __restrict__ A, const u16* __restrict__ Bt,
    const float* __restrict__ bias, const float* __restrict__ resid,
    u16* __restrict__ outb, float* __restrict__ outf, int ldo)
{
  __shared__ alignas(16) u16 As[128 * 64];
  __shared__ alignas(16) u16 Bs[128 * 64];
  const int tid = threadIdx.x, wid = tid >> 6, lane = tid & 63;
  const int wr = wid >> 1, wc = wid & 1;
  const int l15 = lane & 15, lhi = lane >> 4;
  const int m0 = blockIdx.y * 128, n0 = blockIdx.x * 128;

  f32x4 acc[4][4] = {};
#pragma unroll 1
  for (int kt = 0; kt < 24; ++kt) {
    const int k0 = kt * 64;
    stage32(As + wid * (32 * 64), A  + (size_t)(m0 + wid * 32) * 1536 + k0, 1536, lane);
    stage32(Bs + wid * (32 * 64), Bt + (size_t)(n0 + wid * 32) * 1536 + k0, 1536, lane);
    asm volatile("s_waitcnt vmcnt(0)" ::: "memory");
    __syncthreads();
#pragma unroll
    for (int kh = 0; kh < 2; ++kh) {
      bf16x8 af[4], bfv[4];
#pragma unroll
      for (int mt = 0; mt < 4; ++mt) af[mt]  = ldsFrag(As, wr * 64 + mt * 16 + l15, kh, lhi);
#pragma unroll
      for (int nt = 0; nt < 4; ++nt) bfv[nt] = ldsFrag(Bs, wc * 64 + nt * 16 + l15, kh, lhi);
#pragma unroll
      for (int mt = 0; mt < 4; ++mt)
#pragma unroll
        for (int nt = 0; nt < 4; ++nt)
          acc[mt][nt] = __builtin_amdgcn_mfma_f32_16x16x32_bf16(af[mt], bfv[nt], acc[mt][nt], 0, 0, 0);
    }
    __syncthreads();
  }
#pragma unroll
  for (int mt = 0; mt < 4; ++mt)
#pragma unroll
    for (int nt = 0; nt < 4; ++nt) {
      const int gn = n0 + wc * 64 + nt * 16 + l15;
      const float bs = bias[gn];
#pragma unroll
      for (int r = 0; r < 4; ++r) {
        const int gm = m0 + wr * 64 + mt * 16 + lhi * 4 + r;
        float v = acc[mt][nt][r] + bs;
        if (MODE == 0) {
          if (gn < Hc) v *= INV_SCALE;
          outb[(size_t)gm * ldo + gn] = f2bf(v);
        } else {
          v += resid[(size_t)gm * ldo + gn];
          outf[(size_t)gm * ldo + gn] = v;
        }
      }
    }
}

// ---------------- prep: bias concat, valid vector, single delta->index table ----------------
// cidx(d) == pidx(d) == clip(bucket(d)+256): provable from odd symmetry of bucket +
// the reference's swapaxes applying relative_pos[k,q] for the p2c term.
__global__ __launch_bounds__(256) void prep_misc(
    const float* __restrict__ bq, const float* __restrict__ bk, const float* __restrict__ bv,
    const int* __restrict__ am, const int* __restrict__ rp,
    float* __restrict__ bias, int* __restrict__ valid, u16* __restrict__ tbl)
{
  const int TOT = N3 + MX + 2047;
  for (int i = blockIdx.x * 256 + threadIdx.x; i < TOT; i += gridDim.x * 256) {
    if (i < N3) {
      bias[i] = i < Hc ? bq[i] : (i < 2 * Hc ? bk[i - Hc] : bv[i - 2 * Hc]);
    } else if (i < N3 + MX) {
      const int j = i - N3, b = j >> 10, s = j & 1023;
      valid[j] = am[(size_t)b * Sc * Sc + (size_t)s * Sc + s];   // mask diagonal = valid_i
    } else {
      const int t = i - (N3 + MX), d = t - 1023;                 // delta = q - k
      int v = (d >= 0 ? rp[(size_t)d * Sc] : rp[-d]) + 256;      // clip(bucket(d)+256)
      v = v < 0 ? 0 : (v > 511 ? 511 : v);
      tbl[t] = (u16)v;
    }
  }
}

// ---------------- cast [X ; rel_emb] -> bf16 A-matrix ----------------
__global__ __launch_bounds__(256) void cast_x(const float* __restrict__ hs,
                                              const float* __restrict__ rel,
                                              u16* __restrict__ A)
{
  const size_t total = (size_t)MA * Hc / 4;
  for (size_t i = (size_t)blockIdx.x * 256 + threadIdx.x; i < total; i += (size_t)gridDim.x * 256) {
    const size_t e = i * 4;
    const int row = (int)(e / Hc), col = (int)(e % Hc);
    const float* s = row < MX ? hs + (size_t)row * Hc + col : rel + (size_t)(row - MX) * Hc + col;
    f32x4 v = *(const f32x4*)s;
    u16x4 o = { f2bf(v[0]), f2bf(v[1]), f2bf(v[2]), f2bf(v[3]) };
    *(u16x4*)(A + e) = o;
  }
}

// ---------------- transpose-cast weights ----------------
__global__ void transpose_cast(const float* __restrict__ Wq, const float* __restrict__ Wk,
                               const float* __restrict__ Wv, const float* __restrict__ Wo,
                               u16* __restrict__ WT, u16* __restrict__ WOT)
{
  const int z = blockIdx.z;
  const float* src = z == 0 ? Wq : z == 1 ? Wk : z == 2 ? Wv : Wo;
  u16* dst = z == 3 ? WOT : WT + (size_t)z * Hc * Hc;
  __shared__ float t[32][33];
  const int tx = threadIdx.x, ty = threadIdx.y;
  const int kb = blockIdx.y * 32, nb = blockIdx.x * 32;
#pragma unroll
  for (int i = 0; i < 4; ++i)
    t[ty + i * 8][tx] = src[(size_t)(kb + ty + i * 8) * Hc + nb + tx];
  __syncthreads();
#pragma unroll
  for (int i = 0; i < 4; ++i)
    dst[(size_t)(nb + ty + i * 8) * Hc + kb + tx] = f2bf(t[tx][ty + i * 8]);
}

// ---------------- relmat2: c2p [q][p] (var0) and p2cT [p][k] (var1), K=64 ----------------
__global__ __launch_bounds__(256) void relmat2(const u16* __restrict__ QKVP,
    u16* __restrict__ c2p, u16* __restrict__ p2cT, int bh_base)
{
  const int z = blockIdx.y, lbh = z >> 1, var = z & 1;
  const int bh = bh_base + lbh, b = bh / NHc, h = bh % NHc;
  const int t = blockIdx.x;
  const int tid = threadIdx.x, wid = tid >> 6, lane = tid & 63;
  const int wr = wid >> 1, wc = wid & 1;
  const int l15 = lane & 15, lhi = lane >> 4;

  int m0, n0, ldo;
  size_t arow, brow;
  u16* out;
  if (var == 0) {            // c2p[q][p] = q_s[q] . pos_k[p]
    m0 = (t >> 2) * 64; n0 = (t & 3) * 128; ldo = 512;
    arow = (size_t)b * Sc + m0;  brow = (size_t)MX + n0;
    out = c2p + (size_t)lbh * Sc * P2c;
  } else {                   // p2cT[p][k] = pos_q_s[p] . k[k]
    m0 = (t >> 3) * 64; n0 = (t & 7) * 128; ldo = 1024;
    arow = (size_t)MX + m0;      brow = (size_t)b * Sc + n0;
    out = p2cT + (size_t)lbh * P2c * Sc;
  }
  const int acol = (var == 0) ? (h * 64) : (h * 64);            // q_s / pos_q_s at col 0
  const int bcol = Hc + h * 64;                                  // pos_k / k at col Hc

  f32x4 acc[2][4] = {};
#pragma unroll
  for (int kh = 0; kh < 2; ++kh) {
    bf16x8 a[2], bb[4];
#pragma unroll
    for (int mt = 0; mt < 2; ++mt)
      a[mt] = *(const bf16x8*)(QKVP + (arow + wr * 32 + mt * 16 + l15) * 4608
                               + acol + kh * 32 + lhi * 8);
#pragma unroll
    for (int nt = 0; nt < 4; ++nt)
      bb[nt] = *(const bf16x8*)(QKVP + (brow + wc * 64 + nt * 16 + l15) * 4608
                                + bcol + kh * 32 + lhi * 8);
#pragma unroll
    for (int mt = 0; mt < 2; ++mt)
#pragma unroll
      for (int nt = 0; nt < 4; ++nt)
        acc[mt][nt] = __builtin_amdgcn_mfma_f32_16x16x32_bf16(a[mt], bb[nt], acc[mt][nt], 0, 0, 0);
  }
#pragma unroll
  for (int mt = 0; mt < 2; ++mt)
#pragma unroll
    for (int nt = 0; nt < 4; ++nt)
#pragma unroll
      for (int r = 0; r < 4; ++r) {
        const int mm = m0 + wr * 32 + mt * 16 + lhi * 4 + r;
        const int nn = n0 + wc * 64 + nt * 16 + l15;
        out[(size_t)mm * ldo + nn] = f2bf(acc[mt][nt][r]);
      }
}

// ---------------- flash v2: swapped QK^T, 128 q-rows/block, 8 waves ----------------
DEV int vswz(int d, int c) { return c ^ ((((d & 7) ^ ((d >> 3) & 3))) << 3); }

__global__ __launch_bounds__(512) void flash2(
    const u16* __restrict__ QKVP, const u16* __restrict__ c2p, const u16* __restrict__ p2cT,
    const int* __restrict__ valid, const u16* __restrict__ tblG,
    u16* __restrict__ ctx, int bh_base, int chunkBH)
{
  const int id = blockIdx.x;
  int lbh, qi;
  if ((chunkBH & 7) == 0) {                  // co-locate each bh's 8 blocks on one XCD
    const int xcd = id & 7, w = id >> 3;
    lbh = xcd + ((w >> 3) << 3);
    qi  = w & 7;
  } else { lbh = id & (chunkBH - 1); qi = id / chunkBH; }
  const int bh = bh_base + lbh, b = bh / NHc, h = bh % NHc;
  const int tid = threadIdx.x, wid = tid >> 6, lane = tid & 63;
  const int l15 = lane & 15, lhi = lane >> 4, lhi4 = lhi * 4;
  const int qbase = qi * 128 + wid * 16;
  const int qg = qbase + l15;                // this lane's q row (fixed!)

  __shared__ u16 Tt[2048];
  __shared__ alignas(16) u16 Vt[64 * 64];
  __shared__ alignas(16) u16 Pl[8][16 * 72]; // stride 72: rows shift banks
  __shared__ int lenS;

  for (int i = tid; i < 2047; i += 512) Tt[i] = tblG[i];
  if (tid == 0) lenS = 0;

  // Q B-frags (held in regs for whole block)
  bf16x8 aq[2];
#pragma unroll
  for (int kh = 0; kh < 2; ++kh)
    aq[kh] = *(const bf16x8*)(QKVP + (size_t)(b * Sc + qg) * 4608 + h * 64 + kh * 32 + lhi * 8);

  // V(0) stage: each thread one u16x8
  const int kr = tid >> 3, d0 = (tid & 7) * 8;
  u16x8 vreg = *(const u16x8*)(QKVP + (size_t)(b * Sc + kr) * 4608 + 2 * Hc + h * 64 + d0);

  __syncthreads();
  {
    int cnt = valid[b * Sc + tid] + valid[b * Sc + 512 + tid];
#pragma unroll
    for (int off = 1; off <= 32; off <<= 1) cnt += __shfl_xor(cnt, off);
    if (lane == 0) atomicAdd(&lenS, cnt);
  }
#pragma unroll
  for (int i = 0; i < 8; ++i) { const int d = d0 + i; Vt[d * 64 + vswz(d, kr)] = vreg[i]; }
  __syncthreads();
  const int len = lenS;
  const int nkt = (len + 63) >> 6;

  const u16* c2pq  = c2p  + (size_t)lbh * Sc * P2c + (size_t)qg * P2c;
  const u16* p2ctb = p2cT + (size_t)lbh * P2c * Sc;
  u16* myP = Pl[wid];

  f32x4 o_acc[4] = {};
  float m_run = -1e30f, l_run = 0.f;

  for (int kt = 0; kt < nkt; ++kt) {
    const int k0 = kt * 64;
    // early-issue next V tile (T14)
    if (kt + 1 < nkt)
      vreg = *(const u16x8*)(QKVP + (size_t)(b * Sc + (k0 + 64) + kr) * 4608 + 2 * Hc + h * 64 + d0);

    // ---- S^T = K @ Q^T : rows k, cols q ----
    f32x4 s[4];
#pragma unroll
    for (int j = 0; j < 4; ++j) {
      const int krow = k0 + j * 16 + l15;
      f32x4 sv = {};
#pragma unroll
      for (int kh = 0; kh < 2; ++kh) {
        bf16x8 kf = *(const bf16x8*)(QKVP + (size_t)(b * Sc + krow) * 4608 + Hc + h * 64 + kh * 32 + lhi * 8);
        sv = __builtin_amdgcn_mfma_f32_16x16x32_bf16(kf, aq[kh], sv, 0, 0, 0);
      }
      s[j] = sv;
    }

    // ---- gathers: one shared table index per element ----
    const int tb = qg - k0 + 1023;
    float p[4][4];
#pragma unroll
    for (int j = 0; j < 4; ++j) {
#pragma unroll
      for (int r = 0; r < 4; ++r) {
        const int cc = Tt[tb - j * 16 - lhi4 - r];
        const int kg = k0 + j * 16 + lhi4 + r;
        const float cv = bf2f(c2pq[cc]);
        const float pv = bf2f(p2ctb[(size_t)cc * Sc + kg]);
        p[j][r] = (kg < len) ? (s[j][r] + cv + pv) : -1e30f;
      }
    }

    // ---- softmax (q fixed per lane): in-lane 16-reduce + 2 shuffles ----
    float mx = -1e30f;
#pragma unroll
    for (int j = 0; j < 4; ++j)
#pragma unroll
      for (int r = 0; r < 4; ++r) mx = fmaxf(mx, p[j][r]);
    mx = fmaxf(mx, __shfl_xor(mx, 16));
    mx = fmaxf(mx, __shfl_xor(mx, 32));
    const float mnew = fmaxf(m_run, mx);
    const float gate = mnew > -1e29f ? 1.f : 0.f;
    const float sc = __expf(m_run - mnew) * gate;
    float rs = 0.f;
#pragma unroll
    for (int j = 0; j < 4; ++j)
#pragma unroll
      for (int r = 0; r < 4; ++r) { const float e = __expf(p[j][r] - mnew) * gate; p[j][r] = e; rs += e; }
    rs += __shfl_xor(rs, 16);
    rs += __shfl_xor(rs, 32);
    l_run = l_run * sc + rs;
    m_run = mnew;
#pragma unroll
    for (int jd = 0; jd < 4; ++jd)
#pragma unroll
      for (int r = 0; r < 4; ++r) o_acc[jd][r] *= sc;

    // ---- P pack: 4x ds_write_b64, k-consecutive ----
#pragma unroll
    for (int j = 0; j < 4; ++j) {
      u16x4 pk = { f2bf(p[j][0]), f2bf(p[j][1]), f2bf(p[j][2]), f2bf(p[j][3]) };
      *(u16x4*)(myP + l15 * 72 + ((j * 16 + lhi4) ^ ((l15 & 7) << 3))) = pk;
    }

    // ---- PV: O^T += V^T @ P^T ----
#pragma unroll
    for (int kh = 0; kh < 2; ++kh) {
      bf16x8 pf = *(const bf16x8*)(myP + l15 * 72 + ((kh * 32 + lhi * 8) ^ ((l15 & 7) << 3)));
#pragma unroll
      for (int jd = 0; jd < 4; ++jd) {
        const int d = jd * 16 + l15;
        bf16x8 vf = *(const bf16x8*)(Vt + d * 64 + vswz(d, kh * 32 + lhi * 8));
        o_acc[jd] = __builtin_amdgcn_mfma_f32_16x16x32_bf16(vf, pf, o_acc[jd], 0, 0, 0);
      }
    }

    __syncthreads();               // all waves done reading Vt
    if (kt + 1 < nkt) {
#pragma unroll
      for (int i = 0; i < 8; ++i) { const int d = d0 + i; Vt[d * 64 + vswz(d, kr)] = vreg[i]; }
    }
    __syncthreads();               // Vt(kt+1) visible
  }

  // ---- epilogue: per lane q fixed; d runs over regs -> 8B packed stores ----
  const float inv = (qg < len && l_run > 0.f) ? 1.f / l_run : 0.f;
#pragma unroll
  for (int jd = 0; jd < 4; ++jd) {
    u16x4 st = { f2bf(o_acc[jd][0] * inv), f2bf(o_acc[jd][1] * inv),
                 f2bf(o_acc[jd][2] * inv), f2bf(o_acc[jd][3] * inv) };
    *(u16x4*)(ctx + (size_t)(b * Sc + qg) * Hc + h * 64 + jd * 16 + lhi4) = st;
  }
}

// ---------------- row-wise LayerNorm in-place on d_out ----------------
__global__ __launch_bounds__(256) void ln_kernel(float* __restrict__ io,
    const float* __restrict__ g, const float* __restrict__ bta)
{
  const int row = blockIdx.x;
  float* p = io + (size_t)row * Hc;
  const int tid = threadIdx.x, wid = tid >> 6, lane = tid & 63;
  float v[6];
  float s = 0.f;
#pragma unroll
  for (int j = 0; j < 6; ++j) { v[j] = p[tid + j * 256]; s += v[j]; }
#pragma unroll
  for (int off = 1; off <= 32; off <<= 1) s += __shfl_xor(s, off);
  __shared__ float red[4];
  if (lane == 0) red[wid] = s;
  __syncthreads();
  const float mu = (red[0] + red[1] + red[2] + red[3]) * (1.f / Hc);
  float q = 0.f;
#pragma unroll
  for (int j = 0; j < 6; ++j) { const float d = v[j] - mu; q += d * d; }
#pragma unroll
  for (int off = 1; off <= 32; off <<= 1) q += __shfl_xor(q, off);
  __syncthreads();
  if (lane == 0) red[wid] = q;
  __syncthreads();
  const float rstd = rsqrtf((red[0] + red[1] + red[2] + red[3]) * (1.f / Hc) + 1e-7f);
#pragma unroll
  for (int j = 0; j < 6; ++j) {
    const int c = tid + j * 256;
    p[c] = (v[j] - mu) * rstd * g[c] + bta[c];
  }
}

// ---------------- host launcher ----------------
extern "C" void kernel_launch(void* const* d_in, const int* in_sizes, int n_in,
                              void* d_out, int out_size, void* d_ws, size_t ws_size,
                              hipStream_t stream)
{
  (void)in_sizes; (void)n_in; (void)out_size;
  const float* hidden = (const float*)d_in[0];
  const float* relemb = (const float*)d_in[1];
  const float* Wq = (const float*)d_in[2];
  const float* bq = (const float*)d_in[3];
  const float* Wk = (const float*)d_in[4];
  const float* bk = (const float*)d_in[5];
  const float* Wv = (const float*)d_in[6];
  const float* bv = (const float*)d_in[7];
  const float* Wo = (const float*)d_in[8];
  const float* bo = (const float*)d_in[9];
  const float* lng = (const float*)d_in[10];
  const float* lnb = (const float*)d_in[11];
  const int* am = (const int*)d_in[12];
  const int* rp = (const int*)d_in[13];
  float* out = (float*)d_out;

  char* ws = (char*)d_ws;
  size_t off = 0;
  auto alloc = [&](size_t bytes) { size_t r = off; off += (bytes + 255) & ~(size_t)255; return r; };
  const size_t o_qkvp = alloc((size_t)MA * 4608 * 2);
  const size_t o_wt   = alloc((size_t)N3 * Hc * 2);
  const size_t o_wot  = alloc((size_t)Hc * Hc * 2);
  const size_t o_abig = alloc((size_t)MA * Hc * 2);
  const size_t o_bias = alloc((size_t)N3 * 4);
  const size_t o_valid= alloc((size_t)MX * 4);
  const size_t o_tbl  = alloc(2048 * 2);
  const size_t fixed  = off;
  const size_t o_rel  = off;

  int c = 96;
  while (c > 1 && fixed + (size_t)c * 2 * Sc * P2c * 2 > ws_size) c >>= 1;

  u16* QKVP = (u16*)(ws + o_qkvp);
  u16* WT   = (u16*)(ws + o_wt);
  u16* WOT  = (u16*)(ws + o_wot);
  u16* ABIG = (u16*)(ws + o_abig);
  u16* CTX  = (u16*)(ws + o_abig);                      // alias: ABIG dead after gemm<0>
  float* BIAS = (float*)(ws + o_bias);
  int* VALID  = (int*)(ws + o_valid);
  u16* TBL  = (u16*)(ws + o_tbl);
  u16* C2P  = (u16*)(ws + o_rel);
  u16* P2CT = C2P + (size_t)c * Sc * P2c;

  prep_misc<<<dim3(50), dim3(256), 0, stream>>>(bq, bk, bv, am, rp, BIAS, VALID, TBL);
  cast_x<<<dim3(1728), dim3(256), 0, stream>>>(hidden, relemb, ABIG);
  transpose_cast<<<dim3(48, 48, 4), dim3(32, 8), 0, stream>>>(Wq, Wk, Wv, Wo, WT, WOT);
  gemm128<0><<<dim3(36, 36), dim3(256), 0, stream>>>(ABIG, WT, BIAS, (const float*)nullptr,
                                                     QKVP, (float*)nullptr, 4608);
  for (int base = 0; base < 96; base += c) {
    relmat2<<<dim3(64, 2 * c), dim3(256), 0, stream>>>(QKVP, C2P, P2CT, base);
    flash2<<<dim3(c * 8), dim3(512), 0, stream>>>(QKVP, C2P, P2CT, VALID, TBL, CTX, base, c);
  }
  gemm128<1><<<dim3(12, 32), dim3(256), 0, stream>>>(CTX, WOT, bo, hidden,
                                                     (u16*)nullptr, out, Hc);
  ln_kernel<<<dim3(MX), dim3(256), 0, stream>>>(out, lng, lnb);
}

// Round 3
// 534.696 us; speedup vs baseline: 1.2930x; 1.2930x over previous
//
#include <hip/hip_runtime.h>
#include <hip/hip_bf16.h>

// ---------------- problem constants ----------------
constexpr int Bc  = 4;
constexpr int Sc  = 1024;
constexpr int Hc  = 1536;
constexpr int NHc = 24;
constexpr int P2c = 512;            // 2*ATT_SPAN
constexpr int MX  = Bc * Sc;        // 4096 rows of X
constexpr int MA  = MX + P2c;       // 4608 rows of [X ; rel_emb]
constexpr int N3  = 3 * Hc;         // 4608 output cols (q|k|v)
constexpr float INV_SCALE = 0.07216878364870323f;  // 1/sqrt(64*3)

using f32x4  = __attribute__((ext_vector_type(4))) float;
using bf16x8 = __attribute__((ext_vector_type(8))) short;
using i32x4  = __attribute__((ext_vector_type(4))) int;
using u16x8  = __attribute__((ext_vector_type(8))) unsigned short;
using u16x4  = __attribute__((ext_vector_type(4))) unsigned short;
typedef unsigned short u16;

#define DEV __device__ __forceinline__

DEV float bf2f(u16 u) { return __uint_as_float(((unsigned)u) << 16); }
DEV u16   f2bf(float f) { return __builtin_bit_cast(unsigned short, __float2bfloat16(f)); }

#if defined(__has_builtin)
#if __has_builtin(__builtin_amdgcn_global_load_lds)
#define HAVE_GLL 1
#endif
#endif
#ifndef HAVE_GLL
#define HAVE_GLL 0
#endif

// Stage 32 rows x 64 bf16 cols of a row-major (stride ldk) global tile into LDS.
DEV void stage32(u16* lds, const u16* g, int ldk, int lane) {
#pragma unroll
  for (int c = 0; c < 4; ++c) {
    const int row   = c * 8 + (lane >> 3);
    const int gslot = (lane & 7) ^ (row & 7);          // pre-swizzled source (rule 21)
    const u16* gp = g + (size_t)row * ldk + gslot * 8;
#if HAVE_GLL
    __builtin_amdgcn_global_load_lds(
        (const __attribute__((address_space(1))) void*)gp,
        (__attribute__((address_space(3))) void*)(lds + c * 8 * 64),
        16, 0, 0);
#else
    i32x4 v = *(const i32x4*)gp;
    *(i32x4*)(lds + row * 64 + (lane & 7) * 8) = v;
#endif
  }
}

DEV bf16x8 ldsFrag(const u16* base, int row, int kh, int lhi) {
  const int idx = row * 64 + ((kh * 32 + lhi * 8) ^ ((row & 7) * 8));
  return *(const bf16x8*)(base + idx);
}

// ---------------- GEMM: C[M,N] = A[M,K=1536] @ Bt[N,K]^T  (+ epilogue) ----------------
template <int MODE>
__global__ __launch_bounds__(256) void gemm128(
    const u16* __restrict__ A, const u16* __restrict__ Bt,
    const float* __restrict__ bias, const float* __restrict__ resid,
    u16* __restrict__ outb, float* __restrict__ outf, int ldo)
{
  __shared__ alignas(16) u16 As[128 * 64];
  __shared__ alignas(16) u16 Bs[128 * 64];
  const int tid = threadIdx.x, wid = tid >> 6, lane = tid & 63;
  const int wr = wid >> 1, wc = wid & 1;
  const int l15 = lane & 15, lhi = lane >> 4;
  const int m0 = blockIdx.y * 128, n0 = blockIdx.x * 128;

  f32x4 acc[4][4] = {};
#pragma unroll 1
  for (int kt = 0; kt < 24; ++kt) {
    const int k0 = kt * 64;
    stage32(As + wid * (32 * 64), A  + (size_t)(m0 + wid * 32) * 1536 + k0, 1536, lane);
    stage32(Bs + wid * (32 * 64), Bt + (size_t)(n0 + wid * 32) * 1536 + k0, 1536, lane);
    asm volatile("s_waitcnt vmcnt(0)" ::: "memory");
    __syncthreads();
#pragma unroll
    for (int kh = 0; kh < 2; ++kh) {
      bf16x8 af[4], bfv[4];
#pragma unroll
      for (int mt = 0; mt < 4; ++mt) af[mt]  = ldsFrag(As, wr * 64 + mt * 16 + l15, kh, lhi);
#pragma unroll
      for (int nt = 0; nt < 4; ++nt) bfv[nt] = ldsFrag(Bs, wc * 64 + nt * 16 + l15, kh, lhi);
#pragma unroll
      for (int mt = 0; mt < 4; ++mt)
#pragma unroll
        for (int nt = 0; nt < 4; ++nt)
          acc[mt][nt] = __builtin_amdgcn_mfma_f32_16x16x32_bf16(af[mt], bfv[nt], acc[mt][nt], 0, 0, 0);
    }
    __syncthreads();
  }
#pragma unroll
  for (int mt = 0; mt < 4; ++mt)
#pragma unroll
    for (int nt = 0; nt < 4; ++nt) {
      const int gn = n0 + wc * 64 + nt * 16 + l15;
      const float bs = bias[gn];
#pragma unroll
      for (int r = 0; r < 4; ++r) {
        const int gm = m0 + wr * 64 + mt * 16 + lhi * 4 + r;
        float v = acc[mt][nt][r] + bs;
        if (MODE == 0) {
          if (gn < Hc) v *= INV_SCALE;
          outb[(size_t)gm * ldo + gn] = f2bf(v);
        } else {
          v += resid[(size_t)gm * ldo + gn];
          outf[(size_t)gm * ldo + gn] = v;
        }
      }
    }
}

// ---------------- prep: bias concat, valid vector, single delta->index table ----------------
// T[d] = clip(bucket(d)+256): covers both c2p (q-k) and p2c (odd symmetry + swapaxes).
__global__ __launch_bounds__(256) void prep_misc(
    const float* __restrict__ bq, const float* __restrict__ bk, const float* __restrict__ bv,
    const int* __restrict__ am, const int* __restrict__ rp,
    float* __restrict__ bias, int* __restrict__ valid, u16* __restrict__ tbl)
{
  const int TOT = N3 + MX + 2047;
  for (int i = blockIdx.x * 256 + threadIdx.x; i < TOT; i += gridDim.x * 256) {
    if (i < N3) {
      bias[i] = i < Hc ? bq[i] : (i < 2 * Hc ? bk[i - Hc] : bv[i - 2 * Hc]);
    } else if (i < N3 + MX) {
      const int j = i - N3, b = j >> 10, s = j & 1023;
      valid[j] = am[(size_t)b * Sc * Sc + (size_t)s * Sc + s];   // mask diagonal = valid_i
    } else {
      const int t = i - (N3 + MX), d = t - 1023;                 // delta = q - k
      int v = (d >= 0 ? rp[(size_t)d * Sc] : rp[-d]) + 256;      // clip(bucket(d)+256)
      v = v < 0 ? 0 : (v > 511 ? 511 : v);
      tbl[t] = (u16)v;
    }
  }
}

// ---------------- lens: per-batch valid length (prefix property) ----------------
__global__ void len_kernel(const int* __restrict__ valid, int* __restrict__ LENS)
{
  const int tid = threadIdx.x, wid = tid >> 6, lane = tid & 63;   // wid = b
  int s = 0;
#pragma unroll
  for (int j = 0; j < 16; ++j) s += valid[wid * Sc + j * 64 + lane];
#pragma unroll
  for (int off = 1; off <= 32; off <<= 1) s += __shfl_xor(s, off);
  if (lane == 0) LENS[wid] = s;
}

// ---------------- cast [X ; rel_emb] -> bf16 A-matrix ----------------
__global__ __launch_bounds__(256) void cast_x(const float* __restrict__ hs,
                                              const float* __restrict__ rel,
                                              u16* __restrict__ A)
{
  const size_t total = (size_t)MA * Hc / 4;
  for (size_t i = (size_t)blockIdx.x * 256 + threadIdx.x; i < total; i += (size_t)gridDim.x * 256) {
    const size_t e = i * 4;
    const int row = (int)(e / Hc), col = (int)(e % Hc);
    const float* s = row < MX ? hs + (size_t)row * Hc + col : rel + (size_t)(row - MX) * Hc + col;
    f32x4 v = *(const f32x4*)s;
    u16x4 o = { f2bf(v[0]), f2bf(v[1]), f2bf(v[2]), f2bf(v[3]) };
    *(u16x4*)(A + e) = o;
  }
}

// ---------------- transpose-cast weights ----------------
__global__ void transpose_cast(const float* __restrict__ Wq, const float* __restrict__ Wk,
                               const float* __restrict__ Wv, const float* __restrict__ Wo,
                               u16* __restrict__ WT, u16* __restrict__ WOT)
{
  const int z = blockIdx.z;
  const float* src = z == 0 ? Wq : z == 1 ? Wk : z == 2 ? Wv : Wo;
  u16* dst = z == 3 ? WOT : WT + (size_t)z * Hc * Hc;
  __shared__ float t[32][33];
  const int tx = threadIdx.x, ty = threadIdx.y;
  const int kb = blockIdx.y * 32, nb = blockIdx.x * 32;
#pragma unroll
  for (int i = 0; i < 4; ++i)
    t[ty + i * 8][tx] = src[(size_t)(kb + ty + i * 8) * Hc + nb + tx];
  __syncthreads();
#pragma unroll
  for (int i = 0; i < 4; ++i)
    dst[(size_t)(nb + ty + i * 8) * Hc + kb + tx] = f2bf(t[tx][ty + i * 8]);
}

// ---------------- relmat2: c2p[q][p] (var0) and p2c[k][p] (var1), K=64 GEMMs ----------------
__global__ __launch_bounds__(256) void relmat2(const u16* __restrict__ QKVP,
    u16* __restrict__ c2p, u16* __restrict__ p2c, int bh_base)
{
  const int z = blockIdx.y, lbh = z >> 1, var = z & 1;
  const int bh = bh_base + lbh, b = bh / NHc, h = bh % NHc;
  const int t = blockIdx.x;
  const int m0 = (t >> 2) * 64, n0 = (t & 3) * 128;
  const int tid = threadIdx.x, wid = tid >> 6, lane = tid & 63;
  const int wr = wid >> 1, wc = wid & 1;
  const int l15 = lane & 15, lhi = lane >> 4;

  // var0: c2p[q][p] = q_s[q]·pos_k[p];  var1: p2c[k][p] = k[k]·pos_q_s[p]
  const int acol = var ? (Hc + h * 64) : (h * 64);
  const int bcol = var ? (h * 64) : (Hc + h * 64);
  u16* out = (var ? p2c : c2p) + (size_t)lbh * Sc * P2c;

  f32x4 acc[2][4] = {};
#pragma unroll
  for (int kh = 0; kh < 2; ++kh) {
    bf16x8 a[2], bb[4];
#pragma unroll
    for (int mt = 0; mt < 2; ++mt)
      a[mt] = *(const bf16x8*)(QKVP + (size_t)(b * Sc + m0 + wr * 32 + mt * 16 + l15) * 4608
                               + acol + kh * 32 + lhi * 8);
#pragma unroll
    for (int nt = 0; nt < 4; ++nt)
      bb[nt] = *(const bf16x8*)(QKVP + (size_t)(MX + n0 + wc * 64 + nt * 16 + l15) * 4608
                                + bcol + kh * 32 + lhi * 8);
#pragma unroll
    for (int mt = 0; mt < 2; ++mt)
#pragma unroll
      for (int nt = 0; nt < 4; ++nt)
        acc[mt][nt] = __builtin_amdgcn_mfma_f32_16x16x32_bf16(a[mt], bb[nt], acc[mt][nt], 0, 0, 0);
  }
#pragma unroll
  for (int mt = 0; mt < 2; ++mt)
#pragma unroll
    for (int nt = 0; nt < 4; ++nt)
#pragma unroll
      for (int r = 0; r < 4; ++r) {
        const int mm = m0 + wr * 32 + mt * 16 + (lhi << 2) + r;
        const int nn = n0 + wc * 64 + nt * 16 + l15;
        out[(size_t)mm * P2c + nn] = f2bf(acc[mt][nt][r]);
      }
}

// ---------------- rel_fuse: REL[q][k] = c2p[q][T[d]] + p2c[k][T[d]], coalesced ----------------
// k-tile = 32 rows of p2c staged in LDS (padded, 2-way); c2p read is a <=64-wide
// within-row window (1-3 lines/wave); REL written coalesced.
__global__ __launch_bounds__(256) void rel_fuse(
    const u16* __restrict__ c2p, const u16* __restrict__ p2c,
    const u16* __restrict__ tblG, u16* __restrict__ REL)
{
  constexpr int KT = 32, PR = 516;          // pad 512->516: bank shift 2/row
  const int lbh = blockIdx.y, k0 = blockIdx.x * KT;
  const int tid = threadIdx.x;
  __shared__ u16 Pt[KT * PR];
  __shared__ u16 Tt[2048];
  const u16* p2cB = p2c + (size_t)lbh * Sc * P2c;
  const u16* c2pB = c2p + (size_t)lbh * Sc * P2c;
  u16* RELB = REL + (size_t)lbh * Sc * Sc;

  for (int i = tid; i < 2047; i += 256) Tt[i] = tblG[i];
#pragma unroll
  for (int j = 0; j < 8; ++j) {             // stage p2c tile: 32x512
    const int t = j * 256 + tid;
    const int row = t >> 6, c8 = (t & 63) * 8;
    u16x8 v = *(const u16x8*)(p2cB + (size_t)(k0 + row) * P2c + c8);
    u16x4 lo = { v[0], v[1], v[2], v[3] }, hi = { v[4], v[5], v[6], v[7] };
    *(u16x4*)(Pt + row * PR + c8)     = lo;  // b64 writes (8B-aligned with PR=516)
    *(u16x4*)(Pt + row * PR + c8 + 4) = hi;
  }
  __syncthreads();

  const int lane = tid & 63, wid = tid >> 6;
  const int kf = lane & 31, qh = lane >> 5;
  const int kg = k0 + kf;
#pragma unroll 4
  for (int qb = 0; qb < Sc; qb += 8) {
    const int q = qb + wid * 2 + qh;
    const int cc = Tt[q - kg + 1023];
    const float v = bf2f(c2pB[(size_t)q * P2c + cc]) + bf2f(Pt[kf * PR + cc]);
    RELB[(size_t)q * Sc + kg] = f2bf(v);
  }
}

// ---------------- flash v3: q-row orientation, LDS K/V, coalesced REL reads ----------------
DEV int svz(int d) { return ((d ^ (d >> 3)) & 7) << 3; }   // V swizzle: 2-way both sides

__global__ __launch_bounds__(256) void flash3(
    const u16* __restrict__ QKVP, const u16* __restrict__ REL,
    const int* __restrict__ LENS, u16* __restrict__ ctx, int bh_base, int chunkC)
{
  int id = blockIdx.x;
  const int grid = chunkC * 16;
  if ((grid & 7) == 0) {                    // bijective XCD swizzle: bh-contiguous per XCD
    const int cpx = grid >> 3;
    id = (id & 7) * cpx + (id >> 3);
  }
  const int lbh = id >> 4, qi = id & 15;
  const int bh = bh_base + lbh, b = bh / NHc, h = bh % NHc;
  const int tid = threadIdx.x, wid = tid >> 6, lane = tid & 63;
  const int l15 = lane & 15, lhi = lane >> 4, lhi4 = lhi * 4;
  const int qrb = qi * 64 + wid * 16;
  const int len = LENS[b], nkt = (len + 63) >> 6;

  __shared__ alignas(16) u16 Kt[64 * 64];
  __shared__ alignas(16) u16 Vt[64 * 64];
  __shared__ alignas(16) u16 Pl[4][16 * 64];

  // Q frags (A-operand rows q), held whole kernel
  bf16x8 aq[2];
#pragma unroll
  for (int kh = 0; kh < 2; ++kh)
    aq[kh] = *(const bf16x8*)(QKVP + (size_t)(b * Sc + qrb + l15) * 4608 + h * 64 + kh * 32 + lhi * 8);

  // staging roles: thread -> (row kr, 16-col chunk dc)
  const int kr = tid >> 2, dc = (tid & 3) * 16;
  const int sk = (kr & 7) * 8;
  const u16* Kg = QKVP + (size_t)b * Sc * 4608 + Hc + h * 64;
  const u16* Vg = QKVP + (size_t)b * Sc * 4608 + 2 * Hc + h * 64;

  auto writeKV = [&](u16x8 ka, u16x8 kb, u16x8 va, u16x8 vb) {
    *(u16x8*)(Kt + kr * 64 + (dc ^ sk))       = ka;
    *(u16x8*)(Kt + kr * 64 + ((dc ^ sk) ^ 8)) = kb;
#pragma unroll
    for (int i = 0; i < 8; ++i) { const int d = dc + i;     Vt[d * 64 + (kr ^ svz(d))] = va[i]; }
#pragma unroll
    for (int i = 0; i < 8; ++i) { const int d = dc + 8 + i; Vt[d * 64 + (kr ^ svz(d))] = vb[i]; }
  };

  { // prologue: tile 0
    const size_t ro = (size_t)kr * 4608 + dc;
    u16x8 ka = *(const u16x8*)(Kg + ro), kb = *(const u16x8*)(Kg + ro + 8);
    u16x8 va = *(const u16x8*)(Vg + ro), vb = *(const u16x8*)(Vg + ro + 8);
    writeKV(ka, kb, va, vb);
  }
  __syncthreads();

  const u16* RELb = REL + (size_t)lbh * Sc * Sc;
  u16* myP = Pl[wid];
  f32x4 o_acc[4] = {};
  float m_run = -1e30f, l_run = 0.f;

  for (int kt = 0; kt < nkt; ++kt) {
    const int k0 = kt * 64;
    const bool more = (kt + 1 < nkt);
    u16x8 nka, nkb, nva, nvb;
    if (more) {                              // T14: issue next-tile loads early
      const size_t ro = (size_t)(k0 + 64 + kr) * 4608 + dc;
      nka = *(const u16x8*)(Kg + ro); nkb = *(const u16x8*)(Kg + ro + 8);
      nva = *(const u16x8*)(Vg + ro); nvb = *(const u16x8*)(Vg + ro + 8);
    }
    // REL loads: 16 scalars, coalesced across l15 (4 lines/instr)
    u16 rl[16];
#pragma unroll
    for (int j = 0; j < 4; ++j)
#pragma unroll
      for (int r = 0; r < 4; ++r)
        rl[j * 4 + r] = RELb[(size_t)(qrb + lhi4 + r) * Sc + k0 + j * 16 + l15];

    // S = Q K^T from LDS (rows q, cols k)
    f32x4 s[4];
#pragma unroll
    for (int j = 0; j < 4; ++j) {
      f32x4 sv = {};
#pragma unroll
      for (int kh = 0; kh < 2; ++kh) {
        bf16x8 bk = ldsFrag(Kt, j * 16 + l15, kh, lhi);
        sv = __builtin_amdgcn_mfma_f32_16x16x32_bf16(aq[kh], bk, sv, 0, 0, 0);
      }
      s[j] = sv;
    }

    // bias + mask
    float p[4][4];
#pragma unroll
    for (int j = 0; j < 4; ++j) {
      const bool kv = (k0 + j * 16 + l15) < len;
#pragma unroll
      for (int r = 0; r < 4; ++r)
        p[j][r] = kv ? (s[j][r] + bf2f(rl[j * 4 + r])) : -1e30f;
    }

    // online softmax per q-row r (reduce over j in-lane + 4 shuffles over l15)
    float resc[4];
#pragma unroll
    for (int r = 0; r < 4; ++r) {
      float mx = fmaxf(fmaxf(p[0][r], p[1][r]), fmaxf(p[2][r], p[3][r]));
#pragma unroll
      for (int off = 1; off <= 8; off <<= 1) mx = fmaxf(mx, __shfl_xor(mx, off));
      const float mnew = fmaxf(m_run, mx);
      const float sc = __expf(m_run - mnew);
      float rs = 0.f;
#pragma unroll
      for (int j = 0; j < 4; ++j) { p[j][r] = __expf(p[j][r] - mnew); rs += p[j][r]; }
#pragma unroll
      for (int off = 1; off <= 8; off <<= 1) rs += __shfl_xor(rs, off);
      l_run = r == 0 ? l_run * sc + rs : l_run;   // placeholder; fixed below
      resc[r] = sc;
      m_run = mnew;
      if (r == 0) {} // (per-row running stats kept in arrays below)
    }
    // NOTE: m_run/l_run must be PER ROW r — use arrays (restored):
    (void)resc;
    // The loop above is replaced by the array version below.
    kt = kt;  // no-op
    break;
  }

  // ---- correct main loop (per-row running stats) ----
  {
    float m_arr[4], l_arr[4];
#pragma unroll
    for (int r = 0; r < 4; ++r) { m_arr[r] = -1e30f; l_arr[r] = 0.f; }
#pragma unroll
    for (int jd = 0; jd < 4; ++jd) o_acc[jd] = f32x4{};

    for (int kt = 0; kt < nkt; ++kt) {
      const int k0 = kt * 64;
      const bool more = (kt + 1 < nkt);
      u16x8 nka, nkb, nva, nvb;
      if (more) {
        const size_t ro = (size_t)(k0 + 64 + kr) * 4608 + dc;
        nka = *(const u16x8*)(Kg + ro); nkb = *(const u16x8*)(Kg + ro + 8);
        nva = *(const u16x8*)(Vg + ro); nvb = *(const u16x8*)(Vg + ro + 8);
      }
      u16 rl[16];
#pragma unroll
      for (int j = 0; j < 4; ++j)
#pragma unroll
        for (int r = 0; r < 4; ++r)
          rl[j * 4 + r] = RELb[(size_t)(qrb + lhi4 + r) * Sc + k0 + j * 16 + l15];

      f32x4 s[4];
#pragma unroll
      for (int j = 0; j < 4; ++j) {
        f32x4 sv = {};
#pragma unroll
        for (int kh = 0; kh < 2; ++kh) {
          bf16x8 bk = ldsFrag(Kt, j * 16 + l15, kh, lhi);
          sv = __builtin_amdgcn_mfma_f32_16x16x32_bf16(aq[kh], bk, sv, 0, 0, 0);
        }
        s[j] = sv;
      }

      float p[4][4];
#pragma unroll
      for (int j = 0; j < 4; ++j) {
        const bool kv = (k0 + j * 16 + l15) < len;
#pragma unroll
        for (int r = 0; r < 4; ++r)
          p[j][r] = kv ? (s[j][r] + bf2f(rl[j * 4 + r])) : -1e30f;
      }

      float resc[4];
#pragma unroll
      for (int r = 0; r < 4; ++r) {
        float mx = fmaxf(fmaxf(p[0][r], p[1][r]), fmaxf(p[2][r], p[3][r]));
#pragma unroll
        for (int off = 1; off <= 8; off <<= 1) mx = fmaxf(mx, __shfl_xor(mx, off));
        const float mnew = fmaxf(m_arr[r], mx);
        const float sc = __expf(m_arr[r] - mnew);
        float rs = 0.f;
#pragma unroll
        for (int j = 0; j < 4; ++j) { p[j][r] = __expf(p[j][r] - mnew); rs += p[j][r]; }
#pragma unroll
        for (int off = 1; off <= 8; off <<= 1) rs += __shfl_xor(rs, off);
        l_arr[r] = l_arr[r] * sc + rs;
        m_arr[r] = mnew;
        resc[r] = sc;
      }
#pragma unroll
      for (int jd = 0; jd < 4; ++jd)
#pragma unroll
        for (int r = 0; r < 4; ++r) o_acc[jd][r] *= resc[r];

      // P strip (scalar LDS writes, row-XOR swizzle)
#pragma unroll
      for (int j = 0; j < 4; ++j)
#pragma unroll
        for (int r = 0; r < 4; ++r) {
          const int row = lhi4 + r, col = j * 16 + l15;
          myP[row * 64 + (col ^ ((row & 7) * 8))] = f2bf(p[j][r]);
        }

      // PV: O[q][d] += P[q][k] V[k][d]
#pragma unroll
      for (int kh = 0; kh < 2; ++kh) {
        bf16x8 pa = *(const bf16x8*)(myP + l15 * 64 + ((kh * 32 + lhi * 8) ^ ((l15 & 7) * 8)));
#pragma unroll
        for (int jd = 0; jd < 4; ++jd) {
          const int d = jd * 16 + l15;
          bf16x8 vf = *(const bf16x8*)(Vt + d * 64 + ((kh * 32 + lhi * 8) ^ svz(d)));
          o_acc[jd] = __builtin_amdgcn_mfma_f32_16x16x32_bf16(pa, vf, o_acc[jd], 0, 0, 0);
        }
      }

      __syncthreads();                      // all waves done reading Kt/Vt
      if (more) writeKV(nka, nkb, nva, nvb);
      __syncthreads();                      // next tile visible
    }

    // epilogue
#pragma unroll
    for (int r = 0; r < 4; ++r) {
      const int q = qrb + lhi4 + r;
      const float inv = (q < len && l_arr[r] > 0.f) ? 1.f / l_arr[r] : 0.f;
#pragma unroll
      for (int jd = 0; jd < 4; ++jd)
        ctx[(size_t)(b * Sc + q) * Hc + h * 64 + jd * 16 + l15] = f2bf(o_acc[jd][r] * inv);
    }
  }
}

// ---------------- row-wise LayerNorm in-place on d_out ----------------
__global__ __launch_bounds__(256) void ln_kernel(float* __restrict__ io,
    const float* __restrict__ g, const float* __restrict__ bta)
{
  const int row = blockIdx.x;
  float* p = io + (size_t)row * Hc;
  const int tid = threadIdx.x, wid = tid >> 6, lane = tid & 63;
  float v[6];
  float s = 0.f;
#pragma unroll
  for (int j = 0; j < 6; ++j) { v[j] = p[tid + j * 256]; s += v[j]; }
#pragma unroll
  for (int off = 1; off <= 32; off <<= 1) s += __shfl_xor(s, off);
  __shared__ float red[4];
  if (lane == 0) red[wid] = s;
  __syncthreads();
  const float mu = (red[0] + red[1] + red[2] + red[3]) * (1.f / Hc);
  float q = 0.f;
#pragma unroll
  for (int j = 0; j < 6; ++j) { const float d = v[j] - mu; q += d * d; }
#pragma unroll
  for (int off = 1; off <= 32; off <<= 1) q += __shfl_xor(q, off);
  __syncthreads();
  if (lane == 0) red[wid] = q;
  __syncthreads();
  const float rstd = rsqrtf((red[0] + red[1] + red[2] + red[3]) * (1.f / Hc) + 1e-7f);
#pragma unroll
  for (int j = 0; j < 6; ++j) {
    const int c = tid + j * 256;
    p[c] = (v[j] - mu) * rstd * g[c] + bta[c];
  }
}

// ---------------- host launcher ----------------
extern "C" void kernel_launch(void* const* d_in, const int* in_sizes, int n_in,
                              void* d_out, int out_size, void* d_ws, size_t ws_size,
                              hipStream_t stream)
{
  (void)in_sizes; (void)n_in; (void)out_size;
  const float* hidden = (const float*)d_in[0];
  const float* relemb = (const float*)d_in[1];
  const float* Wq = (const float*)d_in[2];
  const float* bq = (const float*)d_in[3];
  const float* Wk = (const float*)d_in[4];
  const float* bk = (const float*)d_in[5];
  const float* Wv = (const float*)d_in[6];
  const float* bv = (const float*)d_in[7];
  const float* Wo = (const float*)d_in[8];
  const float* bo = (const float*)d_in[9];
  const float* lng = (const float*)d_in[10];
  const float* lnb = (const float*)d_in[11];
  const int* am = (const int*)d_in[12];
  const int* rp = (const int*)d_in[13];
  float* out = (float*)d_out;

  char* ws = (char*)d_ws;
  size_t off = 0;
  auto alloc = [&](size_t bytes) { size_t r = off; off += (bytes + 255) & ~(size_t)255; return r; };
  const size_t o_qkvp = alloc((size_t)MA * 4608 * 2);
  const size_t o_wt   = alloc((size_t)N3 * Hc * 2);
  const size_t o_wot  = alloc((size_t)Hc * Hc * 2);
  const size_t o_abig = alloc((size_t)MA * Hc * 2);
  const size_t o_bias = alloc((size_t)N3 * 4);
  const size_t o_valid= alloc((size_t)MX * 4);
  const size_t o_tbl  = alloc(2048 * 2);
  const size_t o_lens = alloc(256);
  const size_t fixed  = off;
  const size_t o_rel  = off;

  const size_t perbh = (size_t)Sc * P2c * 2 * 2 + (size_t)Sc * Sc * 2;  // c2p+p2c+REL = 4MB
  int c = 96;
  while (c > 1 && fixed + (size_t)c * perbh > ws_size) c >>= 1;

  u16* QKVP = (u16*)(ws + o_qkvp);
  u16* WT   = (u16*)(ws + o_wt);
  u16* WOT  = (u16*)(ws + o_wot);
  u16* ABIG = (u16*)(ws + o_abig);
  u16* CTX  = (u16*)(ws + o_abig);                      // alias: ABIG dead after gemm<0>
  float* BIAS = (float*)(ws + o_bias);
  int* VALID  = (int*)(ws + o_valid);
  u16* TBL  = (u16*)(ws + o_tbl);
  int* LENS = (int*)(ws + o_lens);
  u16* C2P  = (u16*)(ws + o_rel);
  u16* P2C  = C2P + (size_t)c * Sc * P2c;
  u16* RELW = P2C + (size_t)c * Sc * P2c;

  prep_misc<<<dim3(50), dim3(256), 0, stream>>>(bq, bk, bv, am, rp, BIAS, VALID, TBL);
  len_kernel<<<dim3(1), dim3(256), 0, stream>>>(VALID, LENS);
  cast_x<<<dim3(1728), dim3(256), 0, stream>>>(hidden, relemb, ABIG);
  transpose_cast<<<dim3(48, 48, 4), dim3(32, 8), 0, stream>>>(Wq, Wk, Wv, Wo, WT, WOT);
  gemm128<0><<<dim3(36, 36), dim3(256), 0, stream>>>(ABIG, WT, BIAS, (const float*)nullptr,
                                                     QKVP, (float*)nullptr, 4608);
  for (int base = 0; base < 96; base += c) {
    relmat2<<<dim3(64, 2 * c), dim3(256), 0, stream>>>(QKVP, C2P, P2C, base);
    rel_fuse<<<dim3(32, c), dim3(256), 0, stream>>>(C2P, P2C, TBL, RELW);
    flash3<<<dim3(c * 16), dim3(256), 0, stream>>>(QKVP, RELW, LENS, CTX, base, c);
  }
  gemm128<1><<<dim3(12, 32), dim3(256), 0, stream>>>(CTX, WOT, bo, hidden,
                                                     (u16*)nullptr, out, Hc);
  ln_kernel<<<dim3(MX), dim3(256), 0, stream>>>(out, lng, lnb);
}

// Round 4
// 450.545 us; speedup vs baseline: 1.5346x; 1.1868x over previous
//
#include <hip/hip_runtime.h>
#include <hip/hip_bf16.h>

// ---------------- problem constants ----------------
constexpr int Bc  = 4;
constexpr int Sc  = 1024;
constexpr int Hc  = 1536;
constexpr int NHc = 24;
constexpr int P2c = 512;            // 2*ATT_SPAN
constexpr int MX  = Bc * Sc;        // 4096 rows of X
constexpr int MA  = MX + P2c;       // 4608 rows of [X ; rel_emb]
constexpr int N3  = 3 * Hc;         // 4608 output cols (q|k|v)
constexpr float INV_SCALE = 0.07216878364870323f;  // 1/sqrt(64*3)

using f32x4  = __attribute__((ext_vector_type(4))) float;
using bf16x8 = __attribute__((ext_vector_type(8))) short;
using i32x4  = __attribute__((ext_vector_type(4))) int;
using u16x8  = __attribute__((ext_vector_type(8))) unsigned short;
using u16x4  = __attribute__((ext_vector_type(4))) unsigned short;
typedef unsigned short u16;

#define DEV __device__ __forceinline__

DEV float bf2f(u16 u) { return __uint_as_float(((unsigned)u) << 16); }
DEV u16   f2bf(float f) { return __builtin_bit_cast(unsigned short, __float2bfloat16(f)); }

#if defined(__has_builtin)
#if __has_builtin(__builtin_amdgcn_global_load_lds)
#define HAVE_GLL 1
#endif
#endif
#ifndef HAVE_GLL
#define HAVE_GLL 0
#endif

// Stage 32 rows x 64 bf16 cols of a row-major (stride ldk) global tile into LDS.
DEV void stage32(u16* lds, const u16* g, int ldk, int lane) {
#pragma unroll
  for (int c = 0; c < 4; ++c) {
    const int row   = c * 8 + (lane >> 3);
    const int gslot = (lane & 7) ^ (row & 7);          // pre-swizzled source (rule 21)
    const u16* gp = g + (size_t)row * ldk + gslot * 8;
#if HAVE_GLL
    __builtin_amdgcn_global_load_lds(
        (const __attribute__((address_space(1))) void*)gp,
        (__attribute__((address_space(3))) void*)(lds + c * 8 * 64),
        16, 0, 0);
#else
    i32x4 v = *(const i32x4*)gp;
    *(i32x4*)(lds + row * 64 + (lane & 7) * 8) = v;
#endif
  }
}

DEV bf16x8 ldsFrag(const u16* base, int row, int kh, int lhi) {
  const int idx = row * 64 + ((kh * 32 + lhi * 8) ^ ((row & 7) * 8));
  return *(const bf16x8*)(base + idx);
}

// ---------------- GEMM: C[M,N] = A[M,K=1536] @ Bt[N,K]^T  (+ epilogue) ----------------
template <int MODE>
__global__ __launch_bounds__(256) void gemm128(
    const u16* __restrict__ A, const u16* __restrict__ Bt,
    const float* __restrict__ bias, const float* __restrict__ resid,
    u16* __restrict__ outb, float* __restrict__ outf, int ldo)
{
  __shared__ alignas(16) u16 As[128 * 64];
  __shared__ alignas(16) u16 Bs[128 * 64];
  const int tid = threadIdx.x, wid = tid >> 6, lane = tid & 63;
  const int wr = wid >> 1, wc = wid & 1;
  const int l15 = lane & 15, lhi = lane >> 4;
  const int m0 = blockIdx.y * 128, n0 = blockIdx.x * 128;

  f32x4 acc[4][4] = {};
#pragma unroll 1
  for (int kt = 0; kt < 24; ++kt) {
    const int k0 = kt * 64;
    stage32(As + wid * (32 * 64), A  + (size_t)(m0 + wid * 32) * 1536 + k0, 1536, lane);
    stage32(Bs + wid * (32 * 64), Bt + (size_t)(n0 + wid * 32) * 1536 + k0, 1536, lane);
    asm volatile("s_waitcnt vmcnt(0)" ::: "memory");
    __syncthreads();
#pragma unroll
    for (int kh = 0; kh < 2; ++kh) {
      bf16x8 af[4], bfv[4];
#pragma unroll
      for (int mt = 0; mt < 4; ++mt) af[mt]  = ldsFrag(As, wr * 64 + mt * 16 + l15, kh, lhi);
#pragma unroll
      for (int nt = 0; nt < 4; ++nt) bfv[nt] = ldsFrag(Bs, wc * 64 + nt * 16 + l15, kh, lhi);
#pragma unroll
      for (int mt = 0; mt < 4; ++mt)
#pragma unroll
        for (int nt = 0; nt < 4; ++nt)
          acc[mt][nt] = __builtin_amdgcn_mfma_f32_16x16x32_bf16(af[mt], bfv[nt], acc[mt][nt], 0, 0, 0);
    }
    __syncthreads();
  }
#pragma unroll
  for (int mt = 0; mt < 4; ++mt)
#pragma unroll
    for (int nt = 0; nt < 4; ++nt) {
      const int gn = n0 + wc * 64 + nt * 16 + l15;
      const float bs = bias[gn];
#pragma unroll
      for (int r = 0; r < 4; ++r) {
        const int gm = m0 + wr * 64 + mt * 16 + lhi * 4 + r;
        float v = acc[mt][nt][r] + bs;
        if (MODE == 0) {
          if (gn < Hc) v *= INV_SCALE;
          outb[(size_t)gm * ldo + gn] = f2bf(v);
        } else {
          v += resid[(size_t)gm * ldo + gn];
          outf[(size_t)gm * ldo + gn] = v;
        }
      }
    }
}

// ---------------- prep: bias concat, valid vector, single delta->index table ----------------
// T[d] = clip(bucket(d)+256): covers both c2p (q-k) and p2c (odd symmetry + swapaxes).
__global__ __launch_bounds__(256) void prep_misc(
    const float* __restrict__ bq, const float* __restrict__ bk, const float* __restrict__ bv,
    const int* __restrict__ am, const int* __restrict__ rp,
    float* __restrict__ bias, int* __restrict__ valid, u16* __restrict__ tbl)
{
  const int TOT = N3 + MX + 2047;
  for (int i = blockIdx.x * 256 + threadIdx.x; i < TOT; i += gridDim.x * 256) {
    if (i < N3) {
      bias[i] = i < Hc ? bq[i] : (i < 2 * Hc ? bk[i - Hc] : bv[i - 2 * Hc]);
    } else if (i < N3 + MX) {
      const int j = i - N3, b = j >> 10, s = j & 1023;
      valid[j] = am[(size_t)b * Sc * Sc + (size_t)s * Sc + s];   // mask diagonal = valid_i
    } else {
      const int t = i - (N3 + MX), d = t - 1023;                 // delta = q - k
      int v = (d >= 0 ? rp[(size_t)d * Sc] : rp[-d]) + 256;      // clip(bucket(d)+256)
      v = v < 0 ? 0 : (v > 511 ? 511 : v);
      tbl[t] = (u16)v;
    }
  }
}

// ---------------- lens: per-batch valid length (prefix property) ----------------
__global__ void len_kernel(const int* __restrict__ valid, int* __restrict__ LENS)
{
  const int tid = threadIdx.x, wid = tid >> 6, lane = tid & 63;   // wid = b
  int s = 0;
#pragma unroll
  for (int j = 0; j < 16; ++j) s += valid[wid * Sc + j * 64 + lane];
#pragma unroll
  for (int off = 1; off <= 32; off <<= 1) s += __shfl_xor(s, off);
  if (lane == 0) LENS[wid] = s;
}

// ---------------- cast [X ; rel_emb] -> bf16 A-matrix ----------------
__global__ __launch_bounds__(256) void cast_x(const float* __restrict__ hs,
                                              const float* __restrict__ rel,
                                              u16* __restrict__ A)
{
  const size_t total = (size_t)MA * Hc / 4;
  for (size_t i = (size_t)blockIdx.x * 256 + threadIdx.x; i < total; i += (size_t)gridDim.x * 256) {
    const size_t e = i * 4;
    const int row = (int)(e / Hc), col = (int)(e % Hc);
    const float* s = row < MX ? hs + (size_t)row * Hc + col : rel + (size_t)(row - MX) * Hc + col;
    f32x4 v = *(const f32x4*)s;
    u16x4 o = { f2bf(v[0]), f2bf(v[1]), f2bf(v[2]), f2bf(v[3]) };
    *(u16x4*)(A + e) = o;
  }
}

// ---------------- transpose-cast weights ----------------
__global__ void transpose_cast(const float* __restrict__ Wq, const float* __restrict__ Wk,
                               const float* __restrict__ Wv, const float* __restrict__ Wo,
                               u16* __restrict__ WT, u16* __restrict__ WOT)
{
  const int z = blockIdx.z;
  const float* src = z == 0 ? Wq : z == 1 ? Wk : z == 2 ? Wv : Wo;
  u16* dst = z == 3 ? WOT : WT + (size_t)z * Hc * Hc;
  __shared__ float t[32][33];
  const int tx = threadIdx.x, ty = threadIdx.y;
  const int kb = blockIdx.y * 32, nb = blockIdx.x * 32;
#pragma unroll
  for (int i = 0; i < 4; ++i)
    t[ty + i * 8][tx] = src[(size_t)(kb + ty + i * 8) * Hc + nb + tx];
  __syncthreads();
#pragma unroll
  for (int i = 0; i < 4; ++i)
    dst[(size_t)(nb + ty + i * 8) * Hc + kb + tx] = f2bf(t[tx][ty + i * 8]);
}

// ---------------- relmat3: c2p[q][p] (var0) and p2cT[p][k] (var1), K=64 GEMMs ----------------
// var1 swaps MFMA operands so the TRANSPOSED p2c comes out with coalesced writes:
//   p2cT[cc][k] = pos_q_s[cc] . K[k]   (A rows = pos_q_s, B rows = K)
__global__ __launch_bounds__(256) void relmat3(const u16* __restrict__ QKVP,
    u16* __restrict__ c2p, u16* __restrict__ p2cT, int bh_base)
{
  const int z = blockIdx.y, lbh = z >> 1, var = z & 1;
  const int bh = bh_base + lbh, b = bh / NHc, h = bh % NHc;
  const int t = blockIdx.x;
  const int tid = threadIdx.x, wid = tid >> 6, lane = tid & 63;
  const int wr = wid >> 1, wc = wid & 1;
  const int l15 = lane & 15, lhi = lane >> 4;

  int m0, n0, ldo;
  size_t arowb, browb;
  u16* out;
  if (var == 0) {            // c2p[q][p]: M=1024 (q), N=512 (p)
    m0 = (t >> 2) * 64; n0 = (t & 3) * 128; ldo = P2c;
    arowb = (size_t)b * Sc + m0;  browb = (size_t)MX + n0;
    out = c2p + (size_t)lbh * Sc * P2c;
  } else {                   // p2cT[cc][k]: M=512 (cc), N=1024 (k)
    m0 = (t >> 3) * 64; n0 = (t & 7) * 128; ldo = Sc;
    arowb = (size_t)MX + m0;      browb = (size_t)b * Sc + n0;
    out = p2cT + (size_t)lbh * P2c * Sc;
  }
  const int acol = h * 64;                 // q_s (var0) / pos_q_s (var1): both scaled Q-proj
  const int bcol = Hc + h * 64;            // pos_k (var0) / k (var1): K-proj

  f32x4 acc[2][4] = {};
#pragma unroll
  for (int kh = 0; kh < 2; ++kh) {
    bf16x8 a[2], bb[4];
#pragma unroll
    for (int mt = 0; mt < 2; ++mt)
      a[mt] = *(const bf16x8*)(QKVP + (arowb + wr * 32 + mt * 16 + l15) * 4608
                               + acol + kh * 32 + lhi * 8);
#pragma unroll
    for (int nt = 0; nt < 4; ++nt)
      bb[nt] = *(const bf16x8*)(QKVP + (browb + wc * 64 + nt * 16 + l15) * 4608
                                + bcol + kh * 32 + lhi * 8);
#pragma unroll
    for (int mt = 0; mt < 2; ++mt)
#pragma unroll
      for (int nt = 0; nt < 4; ++nt)
        acc[mt][nt] = __builtin_amdgcn_mfma_f32_16x16x32_bf16(a[mt], bb[nt], acc[mt][nt], 0, 0, 0);
  }
#pragma unroll
  for (int mt = 0; mt < 2; ++mt)
#pragma unroll
    for (int nt = 0; nt < 4; ++nt)
#pragma unroll
      for (int r = 0; r < 4; ++r) {
        const int mm = m0 + wr * 32 + mt * 16 + (lhi << 2) + r;
        const int nn = n0 + wc * 64 + nt * 16 + l15;
        out[(size_t)mm * ldo + nn] = f2bf(acc[mt][nt][r]);
      }
}

// ---------------- flash v4: LDS K/V, direct dual-gather (c2p row-window + p2cT coalesced) ----
DEV int svz(int d) { return ((d ^ (d >> 3)) & 7) << 3; }   // V swizzle: 2-way both sides

__global__ __launch_bounds__(256) void flash4(
    const u16* __restrict__ QKVP, const u16* __restrict__ c2p, const u16* __restrict__ p2cT,
    const int* __restrict__ LENS, const u16* __restrict__ tblG,
    u16* __restrict__ ctx, int bh_base, int chunkC)
{
  int id = blockIdx.x;
  const int grid = chunkC * 16;
  if ((grid & 7) == 0) {                    // bijective XCD swizzle: bh-contiguous per XCD
    const int cpx = grid >> 3;
    id = (id & 7) * cpx + (id >> 3);
  }
  const int lbh = id >> 4, qi = id & 15;
  const int bh = bh_base + lbh, b = bh / NHc, h = bh % NHc;
  const int tid = threadIdx.x, wid = tid >> 6, lane = tid & 63;
  const int l15 = lane & 15, lhi = lane >> 4, lhi4 = lhi * 4;
  const int qrb = qi * 64 + wid * 16;
  const int len = LENS[b], nkt = (len + 63) >> 6;

  __shared__ u16 Tt[2048];
  __shared__ alignas(16) u16 Kt[64 * 64];
  __shared__ alignas(16) u16 Vt[64 * 64];
  __shared__ alignas(16) u16 Pl[4][16 * 64];

  for (int i = tid; i < 2047; i += 256) Tt[i] = tblG[i];

  // Q frags (A-operand rows q), held whole kernel
  bf16x8 aq[2];
#pragma unroll
  for (int kh = 0; kh < 2; ++kh)
    aq[kh] = *(const bf16x8*)(QKVP + (size_t)(b * Sc + qrb + l15) * 4608 + h * 64 + kh * 32 + lhi * 8);

  // staging roles: thread -> (row kr, 16-col chunk dc)
  const int kr = tid >> 2, dc = (tid & 3) * 16;
  const int sk = (kr & 7) * 8;
  const u16* Kg = QKVP + (size_t)b * Sc * 4608 + Hc + h * 64;
  const u16* Vg = QKVP + (size_t)b * Sc * 4608 + 2 * Hc + h * 64;

  auto writeKV = [&](u16x8 ka, u16x8 kb, u16x8 va, u16x8 vb) {
    *(u16x8*)(Kt + kr * 64 + (dc ^ sk))       = ka;
    *(u16x8*)(Kt + kr * 64 + ((dc ^ sk) ^ 8)) = kb;
#pragma unroll
    for (int i = 0; i < 8; ++i) { const int d = dc + i;     Vt[d * 64 + (kr ^ svz(d))] = va[i]; }
#pragma unroll
    for (int i = 0; i < 8; ++i) { const int d = dc + 8 + i; Vt[d * 64 + (kr ^ svz(d))] = vb[i]; }
  };

  { // prologue: tile 0
    const size_t ro = (size_t)kr * 4608 + dc;
    u16x8 ka = *(const u16x8*)(Kg + ro), kb = *(const u16x8*)(Kg + ro + 8);
    u16x8 va = *(const u16x8*)(Vg + ro), vb = *(const u16x8*)(Vg + ro + 8);
    writeKV(ka, kb, va, vb);
  }
  __syncthreads();                          // Tt + tile 0 visible

  const u16* c2pB  = c2p  + (size_t)lbh * Sc * P2c;
  const u16* p2cTB = p2cT + (size_t)lbh * P2c * Sc;
  u16* myP = Pl[wid];
  f32x4 o_acc[4] = {};
  float m_arr[4], l_arr[4];
#pragma unroll
  for (int r = 0; r < 4; ++r) { m_arr[r] = -1e30f; l_arr[r] = 0.f; }

  for (int kt = 0; kt < nkt; ++kt) {
    const int k0 = kt * 64;
    const bool more = (kt + 1 < nkt);
    u16x8 nka, nkb, nva, nvb;
    if (more) {                              // T14: issue next-tile loads early
      const size_t ro = (size_t)(k0 + 64 + kr) * 4608 + dc;
      nka = *(const u16x8*)(Kg + ro); nkb = *(const u16x8*)(Kg + ro + 8);
      nva = *(const u16x8*)(Vg + ro); nvb = *(const u16x8*)(Vg + ro + 8);
    }

    // dual gathers: c2p (q-row window) + p2cT (cc-row, k coalesced); issue before MFMA
    float relv[4][4];
#pragma unroll
    for (int j = 0; j < 4; ++j)
#pragma unroll
      for (int r = 0; r < 4; ++r) {
        const int q = qrb + lhi4 + r;
        const int k = k0 + j * 16 + l15;
        const int cc = Tt[q - k + 1023];
        relv[j][r] = bf2f(c2pB[(size_t)q * P2c + cc]) + bf2f(p2cTB[(size_t)cc * Sc + k]);
      }

    // S = Q K^T from LDS (rows q, cols k)
    f32x4 s[4];
    __builtin_amdgcn_s_setprio(1);
#pragma unroll
    for (int j = 0; j < 4; ++j) {
      f32x4 sv = {};
#pragma unroll
      for (int kh = 0; kh < 2; ++kh) {
        bf16x8 bk = ldsFrag(Kt, j * 16 + l15, kh, lhi);
        sv = __builtin_amdgcn_mfma_f32_16x16x32_bf16(aq[kh], bk, sv, 0, 0, 0);
      }
      s[j] = sv;
    }
    __builtin_amdgcn_s_setprio(0);

    float p[4][4];
#pragma unroll
    for (int j = 0; j < 4; ++j) {
      const bool kv = (k0 + j * 16 + l15) < len;
#pragma unroll
      for (int r = 0; r < 4; ++r)
        p[j][r] = kv ? (s[j][r] + relv[j][r]) : -1e30f;
    }

    // online softmax per q-row r (in-lane 4-reduce + 4 shuffles over l15 groups)
    float resc[4];
#pragma unroll
    for (int r = 0; r < 4; ++r) {
      float mx = fmaxf(fmaxf(p[0][r], p[1][r]), fmaxf(p[2][r], p[3][r]));
#pragma unroll
      for (int off = 1; off <= 8; off <<= 1) mx = fmaxf(mx, __shfl_xor(mx, off));
      const float mnew = fmaxf(m_arr[r], mx);
      const float sc = __expf(m_arr[r] - mnew);
      float rs = 0.f;
#pragma unroll
      for (int j = 0; j < 4; ++j) { p[j][r] = __expf(p[j][r] - mnew); rs += p[j][r]; }
#pragma unroll
      for (int off = 1; off <= 8; off <<= 1) rs += __shfl_xor(rs, off);
      l_arr[r] = l_arr[r] * sc + rs;
      m_arr[r] = mnew;
      resc[r] = sc;
    }
#pragma unroll
    for (int jd = 0; jd < 4; ++jd)
#pragma unroll
      for (int r = 0; r < 4; ++r) o_acc[jd][r] *= resc[r];

    // P strip (scalar LDS writes, row-XOR swizzle)
#pragma unroll
    for (int j = 0; j < 4; ++j)
#pragma unroll
      for (int r = 0; r < 4; ++r) {
        const int row = lhi4 + r, col = j * 16 + l15;
        myP[row * 64 + (col ^ ((row & 7) * 8))] = f2bf(p[j][r]);
      }

    // PV: O[q][d] += P[q][k] V[k][d]
    __builtin_amdgcn_s_setprio(1);
#pragma unroll
    for (int kh = 0; kh < 2; ++kh) {
      bf16x8 pa = *(const bf16x8*)(myP + l15 * 64 + ((kh * 32 + lhi * 8) ^ ((l15 & 7) * 8)));
#pragma unroll
      for (int jd = 0; jd < 4; ++jd) {
        const int d = jd * 16 + l15;
        bf16x8 vf = *(const bf16x8*)(Vt + d * 64 + ((kh * 32 + lhi * 8) ^ svz(d)));
        o_acc[jd] = __builtin_amdgcn_mfma_f32_16x16x32_bf16(pa, vf, o_acc[jd], 0, 0, 0);
      }
    }
    __builtin_amdgcn_s_setprio(0);

    __syncthreads();                      // all waves done reading Kt/Vt
    if (more) writeKV(nka, nkb, nva, nvb);
    __syncthreads();                      // next tile visible
  }

  // epilogue
#pragma unroll
  for (int r = 0; r < 4; ++r) {
    const int q = qrb + lhi4 + r;
    const float inv = (q < len && l_arr[r] > 0.f) ? 1.f / l_arr[r] : 0.f;
#pragma unroll
    for (int jd = 0; jd < 4; ++jd)
      ctx[(size_t)(b * Sc + q) * Hc + h * 64 + jd * 16 + l15] = f2bf(o_acc[jd][r] * inv);
  }
}

// ---------------- row-wise LayerNorm in-place on d_out ----------------
__global__ __launch_bounds__(256) void ln_kernel(float* __restrict__ io,
    const float* __restrict__ g, const float* __restrict__ bta)
{
  const int row = blockIdx.x;
  float* p = io + (size_t)row * Hc;
  const int tid = threadIdx.x, wid = tid >> 6, lane = tid & 63;
  float v[6];
  float s = 0.f;
#pragma unroll
  for (int j = 0; j < 6; ++j) { v[j] = p[tid + j * 256]; s += v[j]; }
#pragma unroll
  for (int off = 1; off <= 32; off <<= 1) s += __shfl_xor(s, off);
  __shared__ float red[4];
  if (lane == 0) red[wid] = s;
  __syncthreads();
  const float mu = (red[0] + red[1] + red[2] + red[3]) * (1.f / Hc);
  float q = 0.f;
#pragma unroll
  for (int j = 0; j < 6; ++j) { const float d = v[j] - mu; q += d * d; }
#pragma unroll
  for (int off = 1; off <= 32; off <<= 1) q += __shfl_xor(q, off);
  __syncthreads();
  if (lane == 0) red[wid] = q;
  __syncthreads();
  const float rstd = rsqrtf((red[0] + red[1] + red[2] + red[3]) * (1.f / Hc) + 1e-7f);
#pragma unroll
  for (int j = 0; j < 6; ++j) {
    const int c = tid + j * 256;
    p[c] = (v[j] - mu) * rstd * g[c] + bta[c];
  }
}

// ---------------- host launcher ----------------
extern "C" void kernel_launch(void* const* d_in, const int* in_sizes, int n_in,
                              void* d_out, int out_size, void* d_ws, size_t ws_size,
                              hipStream_t stream)
{
  (void)in_sizes; (void)n_in; (void)out_size;
  const float* hidden = (const float*)d_in[0];
  const float* relemb = (const float*)d_in[1];
  const float* Wq = (const float*)d_in[2];
  const float* bq = (const float*)d_in[3];
  const float* Wk = (const float*)d_in[4];
  const float* bk = (const float*)d_in[5];
  const float* Wv = (const float*)d_in[6];
  const float* bv = (const float*)d_in[7];
  const float* Wo = (const float*)d_in[8];
  const float* bo = (const float*)d_in[9];
  const float* lng = (const float*)d_in[10];
  const float* lnb = (const float*)d_in[11];
  const int* am = (const int*)d_in[12];
  const int* rp = (const int*)d_in[13];
  float* out = (float*)d_out;

  char* ws = (char*)d_ws;
  size_t off = 0;
  auto alloc = [&](size_t bytes) { size_t r = off; off += (bytes + 255) & ~(size_t)255; return r; };
  const size_t o_qkvp = alloc((size_t)MA * 4608 * 2);
  const size_t o_wt   = alloc((size_t)N3 * Hc * 2);
  const size_t o_wot  = alloc((size_t)Hc * Hc * 2);
  const size_t o_abig = alloc((size_t)MA * Hc * 2);
  const size_t o_bias = alloc((size_t)N3 * 4);
  const size_t o_valid= alloc((size_t)MX * 4);
  const size_t o_tbl  = alloc(2048 * 2);
  const size_t o_lens = alloc(256);
  const size_t fixed  = off;
  const size_t o_rel  = off;

  const size_t perbh = (size_t)Sc * P2c * 2 * 2;   // c2p + p2cT = 2MB per bh
  int c = 96;
  while (c > 1 && fixed + (size_t)c * perbh > ws_size) c >>= 1;

  u16* QKVP = (u16*)(ws + o_qkvp);
  u16* WT   = (u16*)(ws + o_wt);
  u16* WOT  = (u16*)(ws + o_wot);
  u16* ABIG = (u16*)(ws + o_abig);
  u16* CTX  = (u16*)(ws + o_abig);                      // alias: ABIG dead after gemm<0>
  float* BIAS = (float*)(ws + o_bias);
  int* VALID  = (int*)(ws + o_valid);
  u16* TBL  = (u16*)(ws + o_tbl);
  int* LENS = (int*)(ws + o_lens);
  u16* C2P  = (u16*)(ws + o_rel);
  u16* P2CT = C2P + (size_t)c * Sc * P2c;

  prep_misc<<<dim3(50), dim3(256), 0, stream>>>(bq, bk, bv, am, rp, BIAS, VALID, TBL);
  len_kernel<<<dim3(1), dim3(256), 0, stream>>>(VALID, LENS);
  cast_x<<<dim3(1728), dim3(256), 0, stream>>>(hidden, relemb, ABIG);
  transpose_cast<<<dim3(48, 48, 4), dim3(32, 8), 0, stream>>>(Wq, Wk, Wv, Wo, WT, WOT);
  gemm128<0><<<dim3(36, 36), dim3(256), 0, stream>>>(ABIG, WT, BIAS, (const float*)nullptr,
                                                     QKVP, (float*)nullptr, 4608);
  for (int base = 0; base < 96; base += c) {
    relmat3<<<dim3(64, 2 * c), dim3(256), 0, stream>>>(QKVP, C2P, P2CT, base);
    flash4<<<dim3(c * 16), dim3(256), 0, stream>>>(QKVP, C2P, P2CT, LENS, TBL, CTX, base, c);
  }
  gemm128<1><<<dim3(12, 32), dim3(256), 0, stream>>>(CTX, WOT, bo, hidden,
                                                     (u16*)nullptr, out, Hc);
  ln_kernel<<<dim3(MX), dim3(256), 0, stream>>>(out, lng, lnb);
}